// Round 7
// baseline (183.381 us; speedup 1.0000x reference)
//
#include <hip/hip_runtime.h>
#include <math.h>

#define BB 2
#define TT 2048
#define DD 512
#define FF 2048
#define HH 8
#define BT 4096      // BB*TT
#define NC 32        // TT/64 chunks
#define CK 64        // chunk size

typedef __bf16 bf16_t;
typedef bf16_t bf16x8 __attribute__((ext_vector_type(8)));
typedef bf16_t bf16x4 __attribute__((ext_vector_type(4)));
typedef float f32x4 __attribute__((ext_vector_type(4)));

typedef const __attribute__((address_space(1))) void* gas_p;
typedef __attribute__((address_space(3))) void* las_p;

__device__ __forceinline__ void async16(const void* g, void* l) {
  __builtin_amdgcn_global_load_lds((gas_p)g, (las_p)l, 16, 0, 0);
}

#define PIPE_SYNC(vm) asm volatile("s_waitcnt lgkmcnt(0) vmcnt(" vm ")\n\ts_barrier" ::: "memory")

// ---------------------------------------------------------------- LN1 (wave-per-row) + weight cast fused
__global__ __launch_bounds__(256) void ln_cast_kernel(
    const float* __restrict__ x, const float* __restrict__ g, const float* __restrict__ bb,
    bf16_t* __restrict__ out,
    const float* __restrict__ Wq, const float* __restrict__ Wk,
    const float* __restrict__ Wv, const float* __restrict__ Wo,
    const float* __restrict__ W1, const float* __restrict__ W2,
    bf16_t* __restrict__ wdst) {
  int t = threadIdx.x;
  if (blockIdx.x >= 1024) {
    size_t i = ((size_t)(blockIdx.x - 1024) * 256 + t) * 8;
    const float* src; size_t off;
    if (i < 262144)       { src = Wq; off = i; }
    else if (i < 524288)  { src = Wk; off = i - 262144; }
    else if (i < 786432)  { src = Wv; off = i - 524288; }
    else if (i < 1048576) { src = Wo; off = i - 786432; }
    else if (i < 2097152) { src = W1; off = i - 1048576; }
    else                  { src = W2; off = i - 2097152; }
    float4 a = *(const float4*)(src + off);
    float4 b = *(const float4*)(src + off + 4);
    bf16x8 o;
    o[0] = (bf16_t)a.x; o[1] = (bf16_t)a.y; o[2] = (bf16_t)a.z; o[3] = (bf16_t)a.w;
    o[4] = (bf16_t)b.x; o[5] = (bf16_t)b.y; o[6] = (bf16_t)b.z; o[7] = (bf16_t)b.w;
    *(bf16x8*)(wdst + i) = o;
    return;
  }
  int w = t >> 6, l = t & 63;
  int row = blockIdx.x * 4 + w;
  int c0 = l * 8;
  const float* xr = x + (size_t)row * DD + c0;
  float4 a = *(const float4*)xr;
  float4 b4 = *(const float4*)(xr + 4);
  float s  = a.x + a.y + a.z + a.w + b4.x + b4.y + b4.z + b4.w;
  float sq = a.x*a.x + a.y*a.y + a.z*a.z + a.w*a.w +
             b4.x*b4.x + b4.y*b4.y + b4.z*b4.z + b4.w*b4.w;
  for (int o = 32; o; o >>= 1) { s += __shfl_xor(s, o); sq += __shfl_xor(sq, o); }
  float m = s * (1.f / 512.f);
  float var = sq * (1.f / 512.f) - m * m;
  float r = rsqrtf(var + 1e-5f);
  float4 ga = *(const float4*)(g + c0);  float4 gb = *(const float4*)(g + c0 + 4);
  float4 ba = *(const float4*)(bb + c0); float4 bbv = *(const float4*)(bb + c0 + 4);
  bf16x8 o8;
  o8[0] = (bf16_t)((a.x - m) * r * ga.x + ba.x);
  o8[1] = (bf16_t)((a.y - m) * r * ga.y + ba.y);
  o8[2] = (bf16_t)((a.z - m) * r * ga.z + ba.z);
  o8[3] = (bf16_t)((a.w - m) * r * ga.w + ba.w);
  o8[4] = (bf16_t)((b4.x - m) * r * gb.x + bbv.x);
  o8[5] = (bf16_t)((b4.y - m) * r * gb.y + bbv.y);
  o8[6] = (bf16_t)((b4.z - m) * r * gb.z + bbv.z);
  o8[7] = (bf16_t)((b4.w - m) * r * gb.w + bbv.w);
  *(bf16x8*)(out + (size_t)row * DD + c0) = o8;
}

// ---------------------------------------------------------------- standalone LN (wave-per-row, x2 fp32 -> bf16)
__global__ __launch_bounds__(256) void ln2_kernel(
    const float* __restrict__ x2, const float* __restrict__ g, const float* __restrict__ bb,
    bf16_t* __restrict__ out) {
  int t = threadIdx.x;
  int w = t >> 6, l = t & 63;
  int row = blockIdx.x * 4 + w;
  int c0 = l * 8;
  const float* xr = x2 + (size_t)row * DD + c0;
  float4 a = *(const float4*)xr;
  float4 b4 = *(const float4*)(xr + 4);
  float s  = a.x + a.y + a.z + a.w + b4.x + b4.y + b4.z + b4.w;
  float sq = a.x*a.x + a.y*a.y + a.z*a.z + a.w*a.w +
             b4.x*b4.x + b4.y*b4.y + b4.z*b4.z + b4.w*b4.w;
  for (int o = 32; o; o >>= 1) { s += __shfl_xor(s, o); sq += __shfl_xor(sq, o); }
  float m = s * (1.f / 512.f);
  float var = sq * (1.f / 512.f) - m * m;
  float r = rsqrtf(var + 1e-5f);
  float4 ga = *(const float4*)(g + c0);  float4 gb = *(const float4*)(g + c0 + 4);
  float4 ba = *(const float4*)(bb + c0); float4 bbv = *(const float4*)(bb + c0 + 4);
  bf16x8 o8;
  o8[0] = (bf16_t)((a.x - m) * r * ga.x + ba.x);
  o8[1] = (bf16_t)((a.y - m) * r * ga.y + ba.y);
  o8[2] = (bf16_t)((a.z - m) * r * ga.z + ba.z);
  o8[3] = (bf16_t)((a.w - m) * r * ga.w + ba.w);
  o8[4] = (bf16_t)((b4.x - m) * r * gb.x + bbv.x);
  o8[5] = (bf16_t)((b4.y - m) * r * gb.y + bbv.y);
  o8[6] = (bf16_t)((b4.z - m) * r * gb.z + bbv.z);
  o8[7] = (bf16_t)((b4.w - m) * r * gb.w + bbv.w);
  *(bf16x8*)(out + (size_t)row * DD + c0) = o8;
}

// ---------------------------------------------------------------- pipelined MFMA GEMM, 128x64 tile
// MODE 0: QKV epilogue (ELU feature / mask), bf16 out segmented by 512-col (ldc 512)
// MODE 1: GELU(acc + bias) epilogue, bf16 out ldc 2048 (FFN1)
template<int MODE>
__global__ __launch_bounds__(256) void gemm64q(
    const bf16_t* __restrict__ A, const bf16_t* __restrict__ B, int K, int NT,
    bf16_t* __restrict__ Qo, bf16_t* __restrict__ Ko, bf16_t* __restrict__ Vo,
    const float* __restrict__ bias, const unsigned char* __restrict__ mask) {
  __shared__ __align__(16) bf16_t smem[4 * 6144];
  int tid = threadIdx.x;
  int bid = blockIdx.x;
  int xcd = bid & 7;
  int tmp = bid >> 3;
  int nt = tmp % NT;
  int mt = (tmp / NT) * 8 + xcd;
  int n0 = nt * 64, m0 = mt * 128;
  int elt = tid * 8;
  int srow = elt >> 5, scol = elt & 31;
  const bf16_t* Ag = A + (size_t)(m0 + srow) * K + scol;
  const bf16_t* Bg = B + (size_t)(n0 + srow) * K + scol;
  size_t hstep = (size_t)64 * K;
  const int NS = K >> 5;
#define ISSUE(s) { bf16_t* st = smem + ((s) & 3) * 6144; int k0 = (s) * 32; \
    async16(Ag + k0, st + elt); async16(Ag + k0 + hstep, st + 2048 + elt); \
    async16(Bg + k0, st + 4096 + elt); }
  ISSUE(0); ISSUE(1); ISSUE(2);
  f32x4 acc[4][2] = {};
  int w = tid >> 6, l = tid & 63;
  int wm = (w >> 1) * 64, wn = (w & 1) * 32;
  int fr = l & 15, fk = (l >> 4) * 8;
  for (int i = 0; i < NS; i++) {
    int rem = NS - 1 - i;
    if (rem >= 2)      PIPE_SYNC("6");
    else if (rem == 1) PIPE_SYNC("3");
    else               PIPE_SYNC("0");
    if (i + 3 < NS) ISSUE(i + 3);
    const bf16_t* As = smem + (i & 3) * 6144;
    const bf16_t* Bs = As + 4096;
    bf16x8 af[4], bfr[2];
#pragma unroll
    for (int ii = 0; ii < 4; ii++) af[ii] = *(const bf16x8*)&As[(wm + ii * 16 + fr) * 32 + fk];
#pragma unroll
    for (int j = 0; j < 2; j++) bfr[j] = *(const bf16x8*)&Bs[(wn + j * 16 + fr) * 32 + fk];
#pragma unroll
    for (int ii = 0; ii < 4; ii++)
#pragma unroll
      for (int j = 0; j < 2; j++)
        acc[ii][j] = __builtin_amdgcn_mfma_f32_16x16x32_bf16(af[ii], bfr[j], acc[ii][j], 0, 0, 0);
  }
#undef ISSUE
  __syncthreads();   // fragment reads done; smem reusable for C staging
  int cn = l & 15, cr = (l >> 4) * 4;
  const int CST = 72;          // bf16 stride, 128x64 tile = 18.4KB
  int seg = n0 >> 9;           // (MODE 0) whole block lies in one 512-col segment
#pragma unroll
  for (int i = 0; i < 4; i++) {
#pragma unroll
    for (int r = 0; r < 4; r++) {
      int mrow = wm + i * 16 + cr + r;
      float p = 1.f;
      if (MODE == 0) p = mask[m0 + mrow] ? 0.f : 1.f;
#pragma unroll
      for (int j = 0; j < 2; j++) {
        int ncol = wn + j * 16 + cn;
        float v = acc[i][j][r];
        float ov;
        if (MODE == 0) {
          float e = v > 0.f ? v + 1.f : expf(v);
          ov = seg == 0 ? e : (seg == 1 ? e * p : v * p);
        } else {
          float t2 = v + bias[n0 + ncol];
          ov = 0.5f * t2 * (1.f + erff(t2 * 0.70710678118654752f));
        }
        smem[mrow * CST + ncol] = (bf16_t)ov;
      }
    }
  }
  __syncthreads();
  bf16_t* outp;
  int ldc, ncol0;
  if (MODE == 0) { outp = seg == 0 ? Qo : (seg == 1 ? Ko : Vo); ldc = 512; ncol0 = n0 & 511; }
  else           { outp = Qo; ldc = 2048; ncol0 = n0; }
#pragma unroll
  for (int it = 0; it < 4; it++) {
    int vec = tid + it * 256;
    int row = vec >> 3;
    int col = (vec & 7) * 8;
    bf16x8 v8 = *(const bf16x8*)&smem[row * CST + col];
    *(bf16x8*)(outp + (size_t)(m0 + row) * ldc + ncol0 + col) = v8;
  }
}

// ---------------------------------------------------------------- 64x64-tile GEMM, fp32 out = acc + bias + resid
// Grid 512 blocks = 2 blocks/CU: wave-level overlap hides the per-K-step barrier drain. 32KB LDS.
__global__ __launch_bounds__(256) void gemm_s64(
    const bf16_t* __restrict__ A, const bf16_t* __restrict__ B, int K, int NT,
    const float* __restrict__ bias, const float* __restrict__ resid,
    float* __restrict__ fout) {
  __shared__ __align__(16) bf16_t smem[4 * 4096];
  int tid = threadIdx.x;
  int bid = blockIdx.x;
  int xcd = bid & 7;
  int tmp = bid >> 3;
  int nt = tmp % NT;
  int mt = (tmp / NT) * 8 + xcd;
  int n0 = nt * 64, m0 = mt * 64;
  int elt = tid * 8;
  int srow = elt >> 5, scol = elt & 31;
  const bf16_t* Ag = A + (size_t)(m0 + srow) * K + scol;
  const bf16_t* Bg = B + (size_t)(n0 + srow) * K + scol;
  const int NS = K >> 5;
#define ISSUE(s) { bf16_t* st = smem + ((s) & 3) * 4096; int k0 = (s) * 32; \
    async16(Ag + k0, st + elt); async16(Bg + k0, st + 2048 + elt); }
  ISSUE(0); ISSUE(1); ISSUE(2);
  f32x4 acc[2][2] = {};
  int w = tid >> 6, l = tid & 63;
  int wm = (w >> 1) * 32, wn = (w & 1) * 32;
  int fr = l & 15, fk = (l >> 4) * 8;
  for (int i = 0; i < NS; i++) {
    int rem = NS - 1 - i;
    if (rem >= 2)      PIPE_SYNC("4");
    else if (rem == 1) PIPE_SYNC("2");
    else               PIPE_SYNC("0");
    if (i + 3 < NS) ISSUE(i + 3);
    const bf16_t* As = smem + (i & 3) * 4096;
    const bf16_t* Bs = As + 2048;
    bf16x8 af[2], bfr[2];
#pragma unroll
    for (int ii = 0; ii < 2; ii++) af[ii] = *(const bf16x8*)&As[(wm + ii * 16 + fr) * 32 + fk];
#pragma unroll
    for (int j = 0; j < 2; j++) bfr[j] = *(const bf16x8*)&Bs[(wn + j * 16 + fr) * 32 + fk];
#pragma unroll
    for (int ii = 0; ii < 2; ii++)
#pragma unroll
      for (int j = 0; j < 2; j++)
        acc[ii][j] = __builtin_amdgcn_mfma_f32_16x16x32_bf16(af[ii], bfr[j], acc[ii][j], 0, 0, 0);
  }
#undef ISSUE
  __syncthreads();   // fragment reads done; smem reusable for fp32 C staging
  const int FST = 72;          // 64x72x4B = 18.4KB <= 32KB
  float* smf = (float*)smem;
  int cn = l & 15, cr = (l >> 4) * 4;
#pragma unroll
  for (int ii = 0; ii < 2; ii++)
#pragma unroll
    for (int r = 0; r < 4; r++) {
      int mrow = wm + ii * 16 + cr + r;
#pragma unroll
      for (int j = 0; j < 2; j++)
        smf[mrow * FST + wn + j * 16 + cn] = acc[ii][j][r];
    }
  __syncthreads();
#pragma unroll
  for (int it = 0; it < 4; it++) {
    int vec = tid + it * 256;
    int row = vec >> 4;
    int col = (vec & 15) * 4;
    size_t gidx = (size_t)(m0 + row) * 512 + n0 + col;
    float4 v = *(const float4*)&smf[row * FST + col];
    float4 bi = *(const float4*)(bias + n0 + col);
    float4 rr = *(const float4*)(resid + gidx);
    *(float4*)(fout + gidx) = make_float4(v.x + bi.x + rr.x, v.y + bi.y + rr.y,
                                          v.z + bi.z + rr.z, v.w + bi.w + rr.w);
  }
}

// ------------------------------------------------- Phase A: chunk summaries via MFMA
__global__ __launch_bounds__(256) void chunk_summary_kernel(
    const bf16_t* __restrict__ Kb, const bf16_t* __restrict__ Vb,
    const float* __restrict__ dl, bf16_t* __restrict__ Sst, float* __restrict__ zst) {
  int chunk = blockIdx.x, bh = blockIdx.y;
  int b = bh >> 3, h = bh & 7;
  int t0 = chunk * CK;
  int tid = threadIdx.x;
  const int ST = 72;
  __shared__ __align__(16) bf16_t KTf[64 * ST];
  __shared__ __align__(16) bf16_t KTb[64 * ST];
  __shared__ __align__(16) bf16_t VT [64 * ST];
  float lam = 1.f / (1.f + expf(-dl[h]));
  int lrow = tid >> 2, lq = tid & 3;     // row j = lrow; col block = lq*16
  float wf = powf(lam, (float)(63 - lrow));
  float wb = powf(lam, (float)lrow);
#pragma unroll
  for (int q = 0; q < 2; q++) {
    int c = lq * 16 + q * 8;
    size_t gidx = ((size_t)(b * TT + t0 + lrow)) * DD + (size_t)h * 64 + c;
    bf16x8 k8 = *(const bf16x8*)(Kb + gidx);
    bf16x8 v8 = *(const bf16x8*)(Vb + gidx);
#pragma unroll
    for (int u = 0; u < 8; u++) {
      float kv = (float)k8[u];
      KTf[(c + u) * ST + lrow] = (bf16_t)(kv * wf);
      KTb[(c + u) * ST + lrow] = (bf16_t)(kv * wb);
      VT [(c + u) * ST + lrow] = v8[u];
    }
  }
  __syncthreads();
  int w = tid >> 6, l = tid & 63;
  int dir = w >> 1;               // waves 0,1 -> forward; 2,3 -> backward
  int drow = (w & 1) * 32;        // d-range of this wave
  const bf16_t* KT = dir ? KTb : KTf;
  int fr = l & 15, fk = (l >> 4) * 8;
  bf16x8 afrag[2][2], bfrag[4][2];
#pragma unroll
  for (int ti = 0; ti < 2; ti++) {
    afrag[ti][0] = *(const bf16x8*)&KT[(drow + ti * 16 + fr) * ST + fk];
    afrag[ti][1] = *(const bf16x8*)&KT[(drow + ti * 16 + fr) * ST + 32 + fk];
  }
#pragma unroll
  for (int tj = 0; tj < 4; tj++) {
    bfrag[tj][0] = *(const bf16x8*)&VT[(tj * 16 + fr) * ST + fk];
    bfrag[tj][1] = *(const bf16x8*)&VT[(tj * 16 + fr) * ST + 32 + fk];
  }
  f32x4 acc[2][4] = {};
#pragma unroll
  for (int ti = 0; ti < 2; ti++)
#pragma unroll
    for (int tj = 0; tj < 4; tj++) {
      acc[ti][tj] = __builtin_amdgcn_mfma_f32_16x16x32_bf16(afrag[ti][0], bfrag[tj][0], acc[ti][tj], 0, 0, 0);
      acc[ti][tj] = __builtin_amdgcn_mfma_f32_16x16x32_bf16(afrag[ti][1], bfrag[tj][1], acc[ti][tj], 0, 0, 0);
    }
  // z vectors: z[d] = sum_j Kw[j][d]  (rows of KT are contiguous)
  if (tid < 128) {
    const bf16_t* KTz = (tid >> 6) ? KTb : KTf;
    int d = tid & 63;
    float z = 0.f;
    for (int j = 0; j < 64; j += 8) {
      bf16x8 kz = *(const bf16x8*)&KTz[d * ST + j];
#pragma unroll
      for (int u = 0; u < 8; u++) z += (float)kz[u];
    }
    zst[(((size_t)(tid >> 6) * 16 + bh) * NC + chunk) * 64 + d] = z;
  }
  __syncthreads();   // all LDS reads done; reuse KTf/KTb as S^T staging
  bf16_t* Ss = dir ? KTb : KTf;
  int cr = (l >> 4) * 4, cn = l & 15;
#pragma unroll
  for (int ti = 0; ti < 2; ti++)
#pragma unroll
    for (int tj = 0; tj < 4; tj++)
#pragma unroll
      for (int r = 0; r < 4; r++) {
        int d = drow + ti * 16 + cr + r;
        int e = tj * 16 + cn;
        Ss[e * ST + d] = (bf16_t)acc[ti][tj][r];   // store S^T[e][d]
      }
  __syncthreads();
  size_t bfr = ((size_t)bh * NC + chunk) * 4096;
  size_t bbr = (((size_t)16 + bh) * NC + chunk) * 4096;
#pragma unroll
  for (int it = 0; it < 4; it++) {
    int vec = tid + it * 256;          // 0..1023 = 2 dirs x 512 vectors
    int d2 = vec >> 9;
    int idx = vec & 511;
    int row = idx >> 3, col = (idx & 7) * 8;
    bf16x8 v8 = *(const bf16x8*)((d2 ? KTb : KTf) + row * ST + col);
    *(bf16x8*)(Sst + (d2 ? bbr : bfr) + (size_t)row * 64 + col) = v8;
  }
}

// ------------------------------------------------- Phase B: scan over chunks (full-occupancy: 1 chain/thread)
__global__ __launch_bounds__(256) void scan_kernel(bf16_t* __restrict__ Sst,
                                                   float* __restrict__ zst,
                                                   const float* __restrict__ dl) {
  int sub = blockIdx.x;      // 16 sub-blocks of 256 elements
  int bh  = blockIdx.y;      // 16
  int dir = blockIdx.z;      // 2
  int h = bh & 7;
  int tid = threadIdx.x;
  float lam = 1.f / (1.f + expf(-dl[h]));
  float lamC = powf(lam, 64.f);
  int elem = sub * 256 + tid;
  size_t base = ((size_t)dir * 16 + bh) * (size_t)NC * 4096 + elem;
  float s = 0.f;
  for (int g = 0; g < 4; g++) {
    bf16_t L[8];
#pragma unroll
    for (int i = 0; i < 8; i++) {
      int st = g * 8 + i;
      int c = dir ? (NC - 1 - st) : st;
      L[i] = Sst[base + (size_t)c * 4096];
    }
#pragma unroll
    for (int i = 0; i < 8; i++) {
      int st = g * 8 + i;
      int c = dir ? (NC - 1 - st) : st;
      s = s * lamC + (float)L[i];
      Sst[base + (size_t)c * 4096] = (bf16_t)s;
    }
  }
  if (sub == 0 && tid < 64) {
    size_t zb = ((size_t)dir * 16 + bh) * (size_t)NC * 64 + tid;
    float z = 0.f;
    for (int g = 0; g < 4; g++) {
      float zL[8];
#pragma unroll
      for (int i = 0; i < 8; i++) {
        int st = g * 8 + i;
        int c = dir ? (NC - 1 - st) : st;
        zL[i] = zst[zb + (size_t)c * 64];
      }
#pragma unroll
      for (int i = 0; i < 8; i++) {
        int st = g * 8 + i;
        int c = dir ? (NC - 1 - st) : st;
        z = z * lamC + zL[i];
        zst[zb + (size_t)c * 64] = z;
      }
    }
  }
}

// ------------------------------------------------- Phase C: merged-direction chunk attention, MFMA
#define AST 72
__global__ __launch_bounds__(256) void chunk_attn_kernel(
    const bf16_t* __restrict__ Qb, const bf16_t* __restrict__ Kb, const bf16_t* __restrict__ Vb,
    const bf16_t* __restrict__ Sst, const float* __restrict__ zst, const float* __restrict__ dl,
    bf16_t* __restrict__ attnb) {
  int chunk = blockIdx.x, bh = blockIdx.y;
  int b = bh >> 3, h = bh & 7;
  int t0 = chunk * CK;
  int tid = threadIdx.x;
  __shared__ __align__(16) bf16_t Qa[64 * AST];
  __shared__ __align__(16) bf16_t KA[64 * AST];
  __shared__ __align__(16) bf16_t Vt[64 * AST];
  __shared__ __align__(16) bf16_t Sft[64 * AST];
  __shared__ __align__(16) bf16_t Sbt[64 * AST];
  __shared__ float rowpart[64][16];
  __shared__ float zpf[64], zpb[64];
  __shared__ float den[64];
  __shared__ float pw[72];
  float lam = 1.f / (1.f + expf(-dl[h]));
  if (tid <= 64) pw[tid] = powf(lam, (float)tid);
  int lrow = tid >> 2, lq = tid & 3;
  for (int q = 0; q < 2; q++) {
    int c = lq * 16 + q * 8;
    size_t g = ((size_t)(b * TT + t0 + lrow)) * DD + (size_t)h * 64 + c;
    bf16x8 q8 = *(const bf16x8*)(Qb + g);
    bf16x8 k8 = *(const bf16x8*)(Kb + g);
    bf16x8 v8 = *(const bf16x8*)(Vb + g);
    *(bf16x8*)&Qa[lrow * AST + c] = q8;
    *(bf16x8*)&KA[lrow * AST + c] = k8;
#pragma unroll
    for (int u = 0; u < 8; u++) Vt[(c + u) * AST + lrow] = v8[u];
  }
  {
    int c16 = lq * 16;
    if (chunk > 0) {
      const bf16_t* src = Sst + ((size_t)bh * NC + chunk - 1) * 4096 + (size_t)lrow * 64 + c16;
      *(bf16x8*)&Sft[lrow * AST + c16] = *(const bf16x8*)src;
      *(bf16x8*)&Sft[lrow * AST + c16 + 8] = *(const bf16x8*)(src + 8);
      if (tid < 64) zpf[tid] = zst[((size_t)bh * NC + chunk - 1) * 64 + tid];
    } else {
      bf16x8 z8 = {};
      *(bf16x8*)&Sft[lrow * AST + c16] = z8;
      *(bf16x8*)&Sft[lrow * AST + c16 + 8] = z8;
      if (tid < 64) zpf[tid] = 0.f;
    }
    if (chunk < NC - 1) {
      const bf16_t* src = Sst + (((size_t)16 + bh) * NC + chunk + 1) * 4096 + (size_t)lrow * 64 + c16;
      *(bf16x8*)&Sbt[lrow * AST + c16] = *(const bf16x8*)src;
      *(bf16x8*)&Sbt[lrow * AST + c16 + 8] = *(const bf16x8*)(src + 8);
      if (tid < 64) zpb[tid] = zst[(((size_t)16 + bh) * NC + chunk + 1) * 64 + tid];
    } else {
      bf16x8 z8 = {};
      *(bf16x8*)&Sbt[lrow * AST + c16] = z8;
      *(bf16x8*)&Sbt[lrow * AST + c16 + 8] = z8;
      if (tid < 64) zpb[tid] = 0.f;
    }
  }
  __syncthreads();
  int w = tid >> 6, l = tid & 63;
  int fr = l & 15, fk = (l >> 4) * 8;
  int cr = (l >> 4) * 4, cn = l & 15;
  int ms = w * 16;
  bf16x8 qf0 = *(const bf16x8*)&Qa[(ms + fr) * AST + fk];
  bf16x8 qf1 = *(const bf16x8*)&Qa[(ms + fr) * AST + 32 + fk];
  f32x4 aqk[4] = {};
#pragma unroll
  for (int t = 0; t < 4; t++) {
    bf16x8 kf0 = *(const bf16x8*)&KA[(t * 16 + fr) * AST + fk];
    bf16x8 kf1 = *(const bf16x8*)&KA[(t * 16 + fr) * AST + 32 + fk];
    aqk[t] = __builtin_amdgcn_mfma_f32_16x16x32_bf16(qf0, kf0, aqk[t], 0, 0, 0);
    aqk[t] = __builtin_amdgcn_mfma_f32_16x16x32_bf16(qf1, kf1, aqk[t], 0, 0, 0);
  }
  __syncthreads();
  float rs[4] = {0.f, 0.f, 0.f, 0.f};
#pragma unroll
  for (int t = 0; t < 4; t++) {
#pragma unroll
    for (int r = 0; r < 4; r++) {
      int i = ms + cr + r;
      int j = t * 16 + cn;
      int dd = i > j ? i - j : j - i;
      float v = aqk[t][r] * pw[dd];
      rs[r] += v;
      KA[i * AST + j] = (bf16_t)v;
    }
  }
#pragma unroll
  for (int r = 0; r < 4; r++) rowpart[ms + cr + r][cn] = rs[r];
  __syncthreads();
  bf16x8 af0 = *(const bf16x8*)&KA[(ms + fr) * AST + fk];
  bf16x8 af1 = *(const bf16x8*)&KA[(ms + fr) * AST + 32 + fk];
  f32x4 aY[4] = {}, aSf[4] = {}, aSb[4] = {};
#pragma unroll
  for (int t = 0; t < 4; t++) {
    bf16x8 vf0 = *(const bf16x8*)&Vt[(t * 16 + fr) * AST + fk];
    bf16x8 vf1 = *(const bf16x8*)&Vt[(t * 16 + fr) * AST + 32 + fk];
    aY[t] = __builtin_amdgcn_mfma_f32_16x16x32_bf16(af0, vf0, aY[t], 0, 0, 0);
    aY[t] = __builtin_amdgcn_mfma_f32_16x16x32_bf16(af1, vf1, aY[t], 0, 0, 0);
    bf16x8 sf0 = *(const bf16x8*)&Sft[(t * 16 + fr) * AST + fk];
    bf16x8 sf1 = *(const bf16x8*)&Sft[(t * 16 + fr) * AST + 32 + fk];
    aSf[t] = __builtin_amdgcn_mfma_f32_16x16x32_bf16(qf0, sf0, aSf[t], 0, 0, 0);
    aSf[t] = __builtin_amdgcn_mfma_f32_16x16x32_bf16(qf1, sf1, aSf[t], 0, 0, 0);
    bf16x8 sb0 = *(const bf16x8*)&Sbt[(t * 16 + fr) * AST + fk];
    bf16x8 sb1 = *(const bf16x8*)&Sbt[(t * 16 + fr) * AST + 32 + fk];
    aSb[t] = __builtin_amdgcn_mfma_f32_16x16x32_bf16(qf0, sb0, aSb[t], 0, 0, 0);
    aSb[t] = __builtin_amdgcn_mfma_f32_16x16x32_bf16(qf1, sb1, aSb[t], 0, 0, 0);
  }
  // denominator, all 256 threads: 4 threads per row, shuffle-combine
  {
    int i = tid >> 2, p = tid & 3;
    float s = 0.f;
#pragma unroll
    for (int xx = 0; xx < 4; xx++) s += rowpart[i][p * 4 + xx];
    float czf = 0.f, czb = 0.f;
#pragma unroll
    for (int cc = 0; cc < 2; cc++) {
      int c = p * 16 + cc * 8;
      bf16x8 q8 = *(const bf16x8*)&Qa[i * AST + c];
#pragma unroll
      for (int u = 0; u < 8; u++) { czf += (float)q8[u] * zpf[c + u]; czb += (float)q8[u] * zpb[c + u]; }
    }
    float dsum = s + pw[i + 1] * czf + pw[64 - i] * czb;
    dsum += __shfl_xor(dsum, 1);
    dsum += __shfl_xor(dsum, 2);
    if (p == 0) den[i] = dsum;
  }
  __syncthreads();
#pragma unroll
  for (int t = 0; t < 4; t++) {
#pragma unroll
    for (int r = 0; r < 4; r++) {
      int i = ms + cr + r;
      int e = t * 16 + cn;
      float lrf = pw[i + 1], lrb = pw[64 - i];
      float inv = 1.f / fmaxf(den[i], 1e-6f);
      float val = (aY[t][r] + lrf * aSf[t][r] + lrb * aSb[t][r]) * inv;
      attnb[((size_t)(b * TT + t0 + i)) * DD + (size_t)h * 64 + e] = (bf16_t)val;
    }
  }
}

// ---------------------------------------------------------------- launch
extern "C" void kernel_launch(void* const* d_in, const int* in_sizes, int n_in,
                              void* d_out, int out_size, void* d_ws, size_t ws_size,
                              hipStream_t stream) {
  const float* x   = (const float*)d_in[0];
  const unsigned char* mask = (const unsigned char*)d_in[1];
  const float* Wq  = (const float*)d_in[2];
  const float* Wk  = (const float*)d_in[3];
  const float* Wv  = (const float*)d_in[4];
  const float* Wo  = (const float*)d_in[5];
  const float* bo  = (const float*)d_in[6];
  const float* g1  = (const float*)d_in[7];
  const float* b1  = (const float*)d_in[8];
  const float* g2  = (const float*)d_in[9];
  const float* b2  = (const float*)d_in[10];
  const float* W1  = (const float*)d_in[11];
  const float* bf1 = (const float*)d_in[12];
  const float* W2  = (const float*)d_in[13];
  const float* bf2 = (const float*)d_in[14];
  const float* dl  = (const float*)d_in[15];
  float* out = (float*)d_out;

  float* ws = (float*)d_ws;
  const size_t U = (size_t)BT * DD;  // 2097152 floats
  float* Qr  = ws;
  float* Kr  = ws + U;
  float* Vr  = ws + 2 * U;
  float* R3  = ws + 3 * U;
  float* R4  = ws + 4 * U;
  float* x2  = ws + 5 * U;
  bf16_t* Sstb = (bf16_t*)(ws + 6 * U);
  float* zst = ws + 8 * U;
  bf16_t* wall = (bf16_t*)(ws + 8 * U + 131072);
  bf16_t* Qb    = (bf16_t*)Qr;
  bf16_t* Kb    = (bf16_t*)Kr;
  bf16_t* Vb    = (bf16_t*)Vr;
  bf16_t* xnb   = (bf16_t*)R3;
  bf16_t* attnb = (bf16_t*)R4;
  bf16_t* h2b   = (bf16_t*)Qr;     // Qb dead after chunk_attn
  bf16_t* ffn1b = (bf16_t*)Kr;     // Kb+Vb dead after chunk_attn
  bf16_t* Wob = wall + 786432;
  bf16_t* W1b = wall + 1048576;
  bf16_t* W2b = wall + 2097152;

  ln_cast_kernel<<<1024 + 1536, 256, 0, stream>>>(x, g1, b1, xnb, Wq, Wk, Wv, Wo, W1, W2, wall);
  // QKV: M=4096, N=1536, K=512; 128x64 tiles -> 768 blocks = 3/CU
  gemm64q<0><<<768, 256, 0, stream>>>(xnb, wall, 512, 24, Qb, Kb, Vb, nullptr, mask);
  chunk_summary_kernel<<<dim3(NC, 16), 256, 0, stream>>>(Kb, Vb, dl, Sstb, zst);
  scan_kernel<<<dim3(16, 16, 2), 256, 0, stream>>>(Sstb, zst, dl);
  chunk_attn_kernel<<<dim3(NC, 16), 256, 0, stream>>>(Qb, Kb, Vb, Sstb, zst, dl, attnb);
  // Wo: M=4096, N=512, K=512; 64x64 tiles -> 512 blocks = 2/CU; fused bias+resid -> fp32 x2
  gemm_s64<<<512, 256, 0, stream>>>(attnb, Wob, 512, 8, bo, x, x2);
  ln2_kernel<<<1024, 256, 0, stream>>>(x2, g2, b2, h2b);
  // FFN1: M=4096, N=2048, K=512; 128x64 tiles -> 1024 blocks = 4/CU; GELU epilogue
  gemm64q<1><<<1024, 256, 0, stream>>>(h2b, W1b, 512, 32, ffn1b, nullptr, nullptr, bf1, nullptr);
  // FFN2: M=4096, N=512, K=2048; 64x64 tiles -> 512 blocks = 2/CU; fused bias+resid -> fp32 out
  gemm_s64<<<512, 256, 0, stream>>>(ffn1b, W2b, 2048, 8, bf2, x2, out);
}

// Round 8
// 177.925 us; speedup vs baseline: 1.0307x; 1.0307x over previous
//
#include <hip/hip_runtime.h>
#include <math.h>

#define BB 2
#define TT 2048
#define DD 512
#define FF 2048
#define HH 8
#define BT 4096      // BB*TT
#define NC 32        // TT/64 chunks
#define CK 64        // chunk size

typedef __bf16 bf16_t;
typedef bf16_t bf16x8 __attribute__((ext_vector_type(8)));
typedef bf16_t bf16x4 __attribute__((ext_vector_type(4)));
typedef float f32x4 __attribute__((ext_vector_type(4)));

typedef const __attribute__((address_space(1))) void* gas_p;
typedef __attribute__((address_space(3))) void* las_p;

__device__ __forceinline__ void async16(const void* g, void* l) {
  __builtin_amdgcn_global_load_lds((gas_p)g, (las_p)l, 16, 0, 0);
}

#define PIPE_SYNC(vm) asm volatile("s_waitcnt lgkmcnt(0) vmcnt(" vm ")\n\ts_barrier" ::: "memory")

// ---------------------------------------------------------------- LN1 (wave-per-row) + weight cast fused
__global__ __launch_bounds__(256) void ln_cast_kernel(
    const float* __restrict__ x, const float* __restrict__ g, const float* __restrict__ bb,
    bf16_t* __restrict__ out,
    const float* __restrict__ Wq, const float* __restrict__ Wk,
    const float* __restrict__ Wv, const float* __restrict__ Wo,
    const float* __restrict__ W1, const float* __restrict__ W2,
    bf16_t* __restrict__ wdst) {
  int t = threadIdx.x;
  if (blockIdx.x >= 1024) {
    size_t i = ((size_t)(blockIdx.x - 1024) * 256 + t) * 8;
    const float* src; size_t off;
    if (i < 262144)       { src = Wq; off = i; }
    else if (i < 524288)  { src = Wk; off = i - 262144; }
    else if (i < 786432)  { src = Wv; off = i - 524288; }
    else if (i < 1048576) { src = Wo; off = i - 786432; }
    else if (i < 2097152) { src = W1; off = i - 1048576; }
    else                  { src = W2; off = i - 2097152; }
    float4 a = *(const float4*)(src + off);
    float4 b = *(const float4*)(src + off + 4);
    bf16x8 o;
    o[0] = (bf16_t)a.x; o[1] = (bf16_t)a.y; o[2] = (bf16_t)a.z; o[3] = (bf16_t)a.w;
    o[4] = (bf16_t)b.x; o[5] = (bf16_t)b.y; o[6] = (bf16_t)b.z; o[7] = (bf16_t)b.w;
    *(bf16x8*)(wdst + i) = o;
    return;
  }
  int w = t >> 6, l = t & 63;
  int row = blockIdx.x * 4 + w;
  int c0 = l * 8;
  const float* xr = x + (size_t)row * DD + c0;
  float4 a = *(const float4*)xr;
  float4 b4 = *(const float4*)(xr + 4);
  float s  = a.x + a.y + a.z + a.w + b4.x + b4.y + b4.z + b4.w;
  float sq = a.x*a.x + a.y*a.y + a.z*a.z + a.w*a.w +
             b4.x*b4.x + b4.y*b4.y + b4.z*b4.z + b4.w*b4.w;
  for (int o = 32; o; o >>= 1) { s += __shfl_xor(s, o); sq += __shfl_xor(sq, o); }
  float m = s * (1.f / 512.f);
  float var = sq * (1.f / 512.f) - m * m;
  float r = rsqrtf(var + 1e-5f);
  float4 ga = *(const float4*)(g + c0);  float4 gb = *(const float4*)(g + c0 + 4);
  float4 ba = *(const float4*)(bb + c0); float4 bbv = *(const float4*)(bb + c0 + 4);
  bf16x8 o8;
  o8[0] = (bf16_t)((a.x - m) * r * ga.x + ba.x);
  o8[1] = (bf16_t)((a.y - m) * r * ga.y + ba.y);
  o8[2] = (bf16_t)((a.z - m) * r * ga.z + ba.z);
  o8[3] = (bf16_t)((a.w - m) * r * ga.w + ba.w);
  o8[4] = (bf16_t)((b4.x - m) * r * gb.x + bbv.x);
  o8[5] = (bf16_t)((b4.y - m) * r * gb.y + bbv.y);
  o8[6] = (bf16_t)((b4.z - m) * r * gb.z + bbv.z);
  o8[7] = (bf16_t)((b4.w - m) * r * gb.w + bbv.w);
  *(bf16x8*)(out + (size_t)row * DD + c0) = o8;
}

// ---------------------------------------------------------------- standalone LN (wave-per-row, x2 fp32 -> bf16)
__global__ __launch_bounds__(256) void ln2_kernel(
    const float* __restrict__ x2, const float* __restrict__ g, const float* __restrict__ bb,
    bf16_t* __restrict__ out) {
  int t = threadIdx.x;
  int w = t >> 6, l = t & 63;
  int row = blockIdx.x * 4 + w;
  int c0 = l * 8;
  const float* xr = x2 + (size_t)row * DD + c0;
  float4 a = *(const float4*)xr;
  float4 b4 = *(const float4*)(xr + 4);
  float s  = a.x + a.y + a.z + a.w + b4.x + b4.y + b4.z + b4.w;
  float sq = a.x*a.x + a.y*a.y + a.z*a.z + a.w*a.w +
             b4.x*b4.x + b4.y*b4.y + b4.z*b4.z + b4.w*b4.w;
  for (int o = 32; o; o >>= 1) { s += __shfl_xor(s, o); sq += __shfl_xor(sq, o); }
  float m = s * (1.f / 512.f);
  float var = sq * (1.f / 512.f) - m * m;
  float r = rsqrtf(var + 1e-5f);
  float4 ga = *(const float4*)(g + c0);  float4 gb = *(const float4*)(g + c0 + 4);
  float4 ba = *(const float4*)(bb + c0); float4 bbv = *(const float4*)(bb + c0 + 4);
  bf16x8 o8;
  o8[0] = (bf16_t)((a.x - m) * r * ga.x + ba.x);
  o8[1] = (bf16_t)((a.y - m) * r * ga.y + ba.y);
  o8[2] = (bf16_t)((a.z - m) * r * ga.z + ba.z);
  o8[3] = (bf16_t)((a.w - m) * r * ga.w + ba.w);
  o8[4] = (bf16_t)((b4.x - m) * r * gb.x + bbv.x);
  o8[5] = (bf16_t)((b4.y - m) * r * gb.y + bbv.y);
  o8[6] = (bf16_t)((b4.z - m) * r * gb.z + bbv.z);
  o8[7] = (bf16_t)((b4.w - m) * r * gb.w + bbv.w);
  *(bf16x8*)(out + (size_t)row * DD + c0) = o8;
}

// ---------------------------------------------------------------- pipelined MFMA GEMM  C = A*B^T (128x128 tile)
// MODE 2: GELU(acc + bias) epilogue, bf16 out ldc 2048 (FFN1)
template<int MODE>
__global__ __launch_bounds__(256) void mfma_gemm(
    const bf16_t* __restrict__ A, const bf16_t* __restrict__ B, int K, int NT,
    bf16_t* __restrict__ Ob, const float* __restrict__ bias) {
  __shared__ __align__(16) bf16_t smem[3 * 8192];
  int tid = threadIdx.x;
  int bid = blockIdx.x;
  int xcd = bid & 7;
  int tmp = bid >> 3;
  int nt = tmp % NT;
  int mt = (tmp / NT) * 8 + xcd;
  int n0 = nt * 128, m0 = mt * 128;
  int elt = tid * 8;
  int srow = elt >> 5, scol = elt & 31;
  const bf16_t* Ag = A + (size_t)(m0 + srow) * K + scol;
  const bf16_t* Bg = B + (size_t)(n0 + srow) * K + scol;
  size_t hstep = (size_t)64 * K;
  int NS = K >> 5;
#define ISSUE(s) { bf16_t* st = smem + ((s) % 3) * 8192; int k0 = (s) * 32; \
    async16(Ag + k0, st + elt); async16(Ag + k0 + hstep, st + 2048 + elt); \
    async16(Bg + k0, st + 4096 + elt); async16(Bg + k0 + hstep, st + 6144 + elt); }
  ISSUE(0); ISSUE(1);
  f32x4 acc[4][4] = {};
  int w = tid >> 6, l = tid & 63;
  int wm = (w >> 1) * 64, wn = (w & 1) * 64;
  int fr = l & 15, fk = (l >> 4) * 8;
  for (int i = 0; i < NS; i++) {
    if (i < NS - 1) PIPE_SYNC("4");
    else            PIPE_SYNC("0");
    if (i + 2 < NS) ISSUE(i + 2);
    const bf16_t* As = smem + (i % 3) * 8192;
    const bf16_t* Bs = As + 4096;
    bf16x8 af[4], bfr[4];
#pragma unroll
    for (int ii = 0; ii < 4; ii++) af[ii] = *(const bf16x8*)&As[(wm + ii * 16 + fr) * 32 + fk];
#pragma unroll
    for (int j = 0; j < 4; j++) bfr[j] = *(const bf16x8*)&Bs[(wn + j * 16 + fr) * 32 + fk];
#pragma unroll
    for (int ii = 0; ii < 4; ii++)
#pragma unroll
      for (int j = 0; j < 4; j++)
        acc[ii][j] = __builtin_amdgcn_mfma_f32_16x16x32_bf16(af[ii], bfr[j], acc[ii][j], 0, 0, 0);
  }
#undef ISSUE
  __syncthreads();
  const int CST = 136;
  int cn = l & 15, cr = (l >> 4) * 4;
#pragma unroll
  for (int i = 0; i < 4; i++) {
#pragma unroll
    for (int r = 0; r < 4; r++) {
      int mrow = wm + i * 16 + cr + r;
#pragma unroll
      for (int j = 0; j < 4; j++) {
        int ncol = wn + j * 16 + cn;
        float v = acc[i][j][r];
        float t2 = v + bias[n0 + ncol];
        float ov = 0.5f * t2 * (1.f + erff(t2 * 0.70710678118654752f));
        smem[mrow * CST + ncol] = (bf16_t)ov;
      }
    }
  }
  __syncthreads();
#pragma unroll
  for (int it = 0; it < 8; it++) {
    int vec = tid + it * 256;
    int row = vec >> 4;
    int col = (vec & 15) * 8;
    bf16x8 v8 = *(const bf16x8*)&smem[row * CST + col];
    *(bf16x8*)(Ob + (size_t)(m0 + row) * 2048 + n0 + col) = v8;
  }
}

// ---------------------------------------------------------------- pipelined MFMA GEMM, 128x64 tile (QKV epilogue)
__global__ __launch_bounds__(256) void gemm64q(
    const bf16_t* __restrict__ A, const bf16_t* __restrict__ B, int K, int NT,
    bf16_t* __restrict__ Qo, bf16_t* __restrict__ Ko, bf16_t* __restrict__ Vo,
    const unsigned char* __restrict__ mask) {
  __shared__ __align__(16) bf16_t smem[4 * 6144];
  int tid = threadIdx.x;
  int bid = blockIdx.x;
  int xcd = bid & 7;
  int tmp = bid >> 3;
  int nt = tmp % NT;
  int mt = (tmp / NT) * 8 + xcd;
  int n0 = nt * 64, m0 = mt * 128;
  int elt = tid * 8;
  int srow = elt >> 5, scol = elt & 31;
  const bf16_t* Ag = A + (size_t)(m0 + srow) * K + scol;
  const bf16_t* Bg = B + (size_t)(n0 + srow) * K + scol;
  size_t hstep = (size_t)64 * K;
  const int NS = K >> 5;
#define ISSUE(s) { bf16_t* st = smem + ((s) & 3) * 6144; int k0 = (s) * 32; \
    async16(Ag + k0, st + elt); async16(Ag + k0 + hstep, st + 2048 + elt); \
    async16(Bg + k0, st + 4096 + elt); }
  ISSUE(0); ISSUE(1); ISSUE(2);
  f32x4 acc[4][2] = {};
  int w = tid >> 6, l = tid & 63;
  int wm = (w >> 1) * 64, wn = (w & 1) * 32;
  int fr = l & 15, fk = (l >> 4) * 8;
  for (int i = 0; i < NS; i++) {
    int rem = NS - 1 - i;
    if (rem >= 2)      PIPE_SYNC("6");
    else if (rem == 1) PIPE_SYNC("3");
    else               PIPE_SYNC("0");
    if (i + 3 < NS) ISSUE(i + 3);
    const bf16_t* As = smem + (i & 3) * 6144;
    const bf16_t* Bs = As + 4096;
    bf16x8 af[4], bfr[2];
#pragma unroll
    for (int ii = 0; ii < 4; ii++) af[ii] = *(const bf16x8*)&As[(wm + ii * 16 + fr) * 32 + fk];
#pragma unroll
    for (int j = 0; j < 2; j++) bfr[j] = *(const bf16x8*)&Bs[(wn + j * 16 + fr) * 32 + fk];
#pragma unroll
    for (int ii = 0; ii < 4; ii++)
#pragma unroll
      for (int j = 0; j < 2; j++)
        acc[ii][j] = __builtin_amdgcn_mfma_f32_16x16x32_bf16(af[ii], bfr[j], acc[ii][j], 0, 0, 0);
  }
#undef ISSUE
  __syncthreads();   // fragment reads done; smem reusable for C staging
  int cn = l & 15, cr = (l >> 4) * 4;
  const int CST = 72;          // bf16 stride, 128x64 tile = 18.4KB
  int seg = n0 >> 9;           // whole block lies in one 512-col segment
#pragma unroll
  for (int i = 0; i < 4; i++) {
#pragma unroll
    for (int r = 0; r < 4; r++) {
      int mrow = wm + i * 16 + cr + r;
      float p = mask[m0 + mrow] ? 0.f : 1.f;
#pragma unroll
      for (int j = 0; j < 2; j++) {
        int ncol = wn + j * 16 + cn;
        float v = acc[i][j][r];
        float e = v > 0.f ? v + 1.f : expf(v);
        float ov = seg == 0 ? e : (seg == 1 ? e * p : v * p);
        smem[mrow * CST + ncol] = (bf16_t)ov;
      }
    }
  }
  __syncthreads();
  bf16_t* outp = seg == 0 ? Qo : (seg == 1 ? Ko : Vo);
  int ncol0 = n0 & 511;
#pragma unroll
  for (int it = 0; it < 4; it++) {
    int vec = tid + it * 256;
    int row = vec >> 3;
    int col = (vec & 7) * 8;
    bf16x8 v8 = *(const bf16x8*)&smem[row * CST + col];
    *(bf16x8*)(outp + (size_t)(m0 + row) * 512 + ncol0 + col) = v8;
  }
}

// ---------------------------------------------------------------- 64x64-tile GEMM, fp32 out = acc + bias + resid
// Grid 512 blocks = 2 blocks/CU: wave-level overlap hides the per-K-step barrier drain. 32KB LDS.
__global__ __launch_bounds__(256) void gemm_s64(
    const bf16_t* __restrict__ A, const bf16_t* __restrict__ B, int K, int NT,
    const float* __restrict__ bias, const float* __restrict__ resid,
    float* __restrict__ fout) {
  __shared__ __align__(16) bf16_t smem[4 * 4096];
  int tid = threadIdx.x;
  int bid = blockIdx.x;
  int xcd = bid & 7;
  int tmp = bid >> 3;
  int nt = tmp % NT;
  int mt = (tmp / NT) * 8 + xcd;
  int n0 = nt * 64, m0 = mt * 64;
  int elt = tid * 8;
  int srow = elt >> 5, scol = elt & 31;
  const bf16_t* Ag = A + (size_t)(m0 + srow) * K + scol;
  const bf16_t* Bg = B + (size_t)(n0 + srow) * K + scol;
  const int NS = K >> 5;
#define ISSUE(s) { bf16_t* st = smem + ((s) & 3) * 4096; int k0 = (s) * 32; \
    async16(Ag + k0, st + elt); async16(Bg + k0, st + 2048 + elt); }
  ISSUE(0); ISSUE(1); ISSUE(2);
  f32x4 acc[2][2] = {};
  int w = tid >> 6, l = tid & 63;
  int wm = (w >> 1) * 32, wn = (w & 1) * 32;
  int fr = l & 15, fk = (l >> 4) * 8;
  for (int i = 0; i < NS; i++) {
    int rem = NS - 1 - i;
    if (rem >= 2)      PIPE_SYNC("4");
    else if (rem == 1) PIPE_SYNC("2");
    else               PIPE_SYNC("0");
    if (i + 3 < NS) ISSUE(i + 3);
    const bf16_t* As = smem + (i & 3) * 4096;
    const bf16_t* Bs = As + 2048;
    bf16x8 af[2], bfr[2];
#pragma unroll
    for (int ii = 0; ii < 2; ii++) af[ii] = *(const bf16x8*)&As[(wm + ii * 16 + fr) * 32 + fk];
#pragma unroll
    for (int j = 0; j < 2; j++) bfr[j] = *(const bf16x8*)&Bs[(wn + j * 16 + fr) * 32 + fk];
#pragma unroll
    for (int ii = 0; ii < 2; ii++)
#pragma unroll
      for (int j = 0; j < 2; j++)
        acc[ii][j] = __builtin_amdgcn_mfma_f32_16x16x32_bf16(af[ii], bfr[j], acc[ii][j], 0, 0, 0);
  }
#undef ISSUE
  __syncthreads();   // fragment reads done; smem reusable for fp32 C staging
  const int FST = 72;          // 64x72x4B = 18.4KB <= 32KB
  float* smf = (float*)smem;
  int cn = l & 15, cr = (l >> 4) * 4;
#pragma unroll
  for (int ii = 0; ii < 2; ii++)
#pragma unroll
    for (int r = 0; r < 4; r++) {
      int mrow = wm + ii * 16 + cr + r;
#pragma unroll
      for (int j = 0; j < 2; j++)
        smf[mrow * FST + wn + j * 16 + cn] = acc[ii][j][r];
    }
  __syncthreads();
#pragma unroll
  for (int it = 0; it < 4; it++) {
    int vec = tid + it * 256;
    int row = vec >> 4;
    int col = (vec & 15) * 4;
    size_t gidx = (size_t)(m0 + row) * 512 + n0 + col;
    float4 v = *(const float4*)&smf[row * FST + col];
    float4 bi = *(const float4*)(bias + n0 + col);
    float4 rr = *(const float4*)(resid + gidx);
    *(float4*)(fout + gidx) = make_float4(v.x + bi.x + rr.x, v.y + bi.y + rr.y,
                                          v.z + bi.z + rr.z, v.w + bi.w + rr.w);
  }
}

// ------------------------------------------------- Phase A: chunk summaries via MFMA
__global__ __launch_bounds__(256) void chunk_summary_kernel(
    const bf16_t* __restrict__ Kb, const bf16_t* __restrict__ Vb,
    const float* __restrict__ dl, bf16_t* __restrict__ Sst, float* __restrict__ zst) {
  int chunk = blockIdx.x, bh = blockIdx.y;
  int b = bh >> 3, h = bh & 7;
  int t0 = chunk * CK;
  int tid = threadIdx.x;
  const int ST = 72;
  __shared__ __align__(16) bf16_t KTf[64 * ST];
  __shared__ __align__(16) bf16_t KTb[64 * ST];
  __shared__ __align__(16) bf16_t VT [64 * ST];
  float lam = 1.f / (1.f + expf(-dl[h]));
  int lrow = tid >> 2, lq = tid & 3;     // row j = lrow; col block = lq*16
  float wf = powf(lam, (float)(63 - lrow));
  float wb = powf(lam, (float)lrow);
#pragma unroll
  for (int q = 0; q < 2; q++) {
    int c = lq * 16 + q * 8;
    size_t gidx = ((size_t)(b * TT + t0 + lrow)) * DD + (size_t)h * 64 + c;
    bf16x8 k8 = *(const bf16x8*)(Kb + gidx);
    bf16x8 v8 = *(const bf16x8*)(Vb + gidx);
#pragma unroll
    for (int u = 0; u < 8; u++) {
      float kv = (float)k8[u];
      KTf[(c + u) * ST + lrow] = (bf16_t)(kv * wf);
      KTb[(c + u) * ST + lrow] = (bf16_t)(kv * wb);
      VT [(c + u) * ST + lrow] = v8[u];
    }
  }
  __syncthreads();
  int w = tid >> 6, l = tid & 63;
  int dir = w >> 1;               // waves 0,1 -> forward; 2,3 -> backward
  int drow = (w & 1) * 32;        // d-range of this wave
  const bf16_t* KT = dir ? KTb : KTf;
  int fr = l & 15, fk = (l >> 4) * 8;
  bf16x8 afrag[2][2], bfrag[4][2];
#pragma unroll
  for (int ti = 0; ti < 2; ti++) {
    afrag[ti][0] = *(const bf16x8*)&KT[(drow + ti * 16 + fr) * ST + fk];
    afrag[ti][1] = *(const bf16x8*)&KT[(drow + ti * 16 + fr) * ST + 32 + fk];
  }
#pragma unroll
  for (int tj = 0; tj < 4; tj++) {
    bfrag[tj][0] = *(const bf16x8*)&VT[(tj * 16 + fr) * ST + fk];
    bfrag[tj][1] = *(const bf16x8*)&VT[(tj * 16 + fr) * ST + 32 + fk];
  }
  f32x4 acc[2][4] = {};
#pragma unroll
  for (int ti = 0; ti < 2; ti++)
#pragma unroll
    for (int tj = 0; tj < 4; tj++) {
      acc[ti][tj] = __builtin_amdgcn_mfma_f32_16x16x32_bf16(afrag[ti][0], bfrag[tj][0], acc[ti][tj], 0, 0, 0);
      acc[ti][tj] = __builtin_amdgcn_mfma_f32_16x16x32_bf16(afrag[ti][1], bfrag[tj][1], acc[ti][tj], 0, 0, 0);
    }
  // z vectors: z[d] = sum_j Kw[j][d]  (rows of KT are contiguous)
  if (tid < 128) {
    const bf16_t* KTz = (tid >> 6) ? KTb : KTf;
    int d = tid & 63;
    float z = 0.f;
    for (int j = 0; j < 64; j += 8) {
      bf16x8 kz = *(const bf16x8*)&KTz[d * ST + j];
#pragma unroll
      for (int u = 0; u < 8; u++) z += (float)kz[u];
    }
    zst[(((size_t)(tid >> 6) * 16 + bh) * NC + chunk) * 64 + d] = z;
  }
  __syncthreads();   // all LDS reads done; reuse KTf/KTb as S^T staging
  bf16_t* Ss = dir ? KTb : KTf;
  int cr = (l >> 4) * 4, cn = l & 15;
#pragma unroll
  for (int ti = 0; ti < 2; ti++)
#pragma unroll
    for (int tj = 0; tj < 4; tj++)
#pragma unroll
      for (int r = 0; r < 4; r++) {
        int d = drow + ti * 16 + cr + r;
        int e = tj * 16 + cn;
        Ss[e * ST + d] = (bf16_t)acc[ti][tj][r];   // store S^T[e][d]
      }
  __syncthreads();
  size_t bfr = ((size_t)bh * NC + chunk) * 4096;
  size_t bbr = (((size_t)16 + bh) * NC + chunk) * 4096;
#pragma unroll
  for (int it = 0; it < 4; it++) {
    int vec = tid + it * 256;          // 0..1023 = 2 dirs x 512 vectors
    int d2 = vec >> 9;
    int idx = vec & 511;
    int row = idx >> 3, col = (idx & 7) * 8;
    bf16x8 v8 = *(const bf16x8*)((d2 ? KTb : KTf) + row * ST + col);
    *(bf16x8*)(Sst + (d2 ? bbr : bfr) + (size_t)row * 64 + col) = v8;
  }
}

// ------------------------------------------------- Phase B: scan over chunks (full-occupancy: 1 chain/thread)
__global__ __launch_bounds__(256) void scan_kernel(bf16_t* __restrict__ Sst,
                                                   float* __restrict__ zst,
                                                   const float* __restrict__ dl) {
  int sub = blockIdx.x;      // 16 sub-blocks of 256 elements
  int bh  = blockIdx.y;      // 16
  int dir = blockIdx.z;      // 2
  int h = bh & 7;
  int tid = threadIdx.x;
  float lam = 1.f / (1.f + expf(-dl[h]));
  float lamC = powf(lam, 64.f);
  int elem = sub * 256 + tid;
  size_t base = ((size_t)dir * 16 + bh) * (size_t)NC * 4096 + elem;
  float s = 0.f;
  for (int g = 0; g < 4; g++) {
    bf16_t L[8];
#pragma unroll
    for (int i = 0; i < 8; i++) {
      int st = g * 8 + i;
      int c = dir ? (NC - 1 - st) : st;
      L[i] = Sst[base + (size_t)c * 4096];
    }
#pragma unroll
    for (int i = 0; i < 8; i++) {
      int st = g * 8 + i;
      int c = dir ? (NC - 1 - st) : st;
      s = s * lamC + (float)L[i];
      Sst[base + (size_t)c * 4096] = (bf16_t)s;
    }
  }
  if (sub == 0 && tid < 64) {
    size_t zb = ((size_t)dir * 16 + bh) * (size_t)NC * 64 + tid;
    float z = 0.f;
    for (int g = 0; g < 4; g++) {
      float zL[8];
#pragma unroll
      for (int i = 0; i < 8; i++) {
        int st = g * 8 + i;
        int c = dir ? (NC - 1 - st) : st;
        zL[i] = zst[zb + (size_t)c * 64];
      }
#pragma unroll
      for (int i = 0; i < 8; i++) {
        int st = g * 8 + i;
        int c = dir ? (NC - 1 - st) : st;
        z = z * lamC + zL[i];
        zst[zb + (size_t)c * 64] = z;
      }
    }
  }
}

// ------------------------------------------------- Phase C: merged-direction chunk attention, MFMA
#define AST 72
__global__ __launch_bounds__(256) void chunk_attn_kernel(
    const bf16_t* __restrict__ Qb, const bf16_t* __restrict__ Kb, const bf16_t* __restrict__ Vb,
    const bf16_t* __restrict__ Sst, const float* __restrict__ zst, const float* __restrict__ dl,
    bf16_t* __restrict__ attnb) {
  int chunk = blockIdx.x, bh = blockIdx.y;
  int b = bh >> 3, h = bh & 7;
  int t0 = chunk * CK;
  int tid = threadIdx.x;
  __shared__ __align__(16) bf16_t Qa[64 * AST];
  __shared__ __align__(16) bf16_t KA[64 * AST];
  __shared__ __align__(16) bf16_t Vt[64 * AST];
  __shared__ __align__(16) bf16_t Sft[64 * AST];
  __shared__ __align__(16) bf16_t Sbt[64 * AST];
  __shared__ float rowpart[64][16];
  __shared__ float zpf[64], zpb[64];
  __shared__ float den[64];
  __shared__ float pw[72];
  float lam = 1.f / (1.f + expf(-dl[h]));
  if (tid <= 64) pw[tid] = powf(lam, (float)tid);
  int lrow = tid >> 2, lq = tid & 3;
  for (int q = 0; q < 2; q++) {
    int c = lq * 16 + q * 8;
    size_t g = ((size_t)(b * TT + t0 + lrow)) * DD + (size_t)h * 64 + c;
    bf16x8 q8 = *(const bf16x8*)(Qb + g);
    bf16x8 k8 = *(const bf16x8*)(Kb + g);
    bf16x8 v8 = *(const bf16x8*)(Vb + g);
    *(bf16x8*)&Qa[lrow * AST + c] = q8;
    *(bf16x8*)&KA[lrow * AST + c] = k8;
#pragma unroll
    for (int u = 0; u < 8; u++) Vt[(c + u) * AST + lrow] = v8[u];
  }
  {
    int c16 = lq * 16;
    if (chunk > 0) {
      const bf16_t* src = Sst + ((size_t)bh * NC + chunk - 1) * 4096 + (size_t)lrow * 64 + c16;
      *(bf16x8*)&Sft[lrow * AST + c16] = *(const bf16x8*)src;
      *(bf16x8*)&Sft[lrow * AST + c16 + 8] = *(const bf16x8*)(src + 8);
      if (tid < 64) zpf[tid] = zst[((size_t)bh * NC + chunk - 1) * 64 + tid];
    } else {
      bf16x8 z8 = {};
      *(bf16x8*)&Sft[lrow * AST + c16] = z8;
      *(bf16x8*)&Sft[lrow * AST + c16 + 8] = z8;
      if (tid < 64) zpf[tid] = 0.f;
    }
    if (chunk < NC - 1) {
      const bf16_t* src = Sst + (((size_t)16 + bh) * NC + chunk + 1) * 4096 + (size_t)lrow * 64 + c16;
      *(bf16x8*)&Sbt[lrow * AST + c16] = *(const bf16x8*)src;
      *(bf16x8*)&Sbt[lrow * AST + c16 + 8] = *(const bf16x8*)(src + 8);
      if (tid < 64) zpb[tid] = zst[(((size_t)16 + bh) * NC + chunk + 1) * 64 + tid];
    } else {
      bf16x8 z8 = {};
      *(bf16x8*)&Sbt[lrow * AST + c16] = z8;
      *(bf16x8*)&Sbt[lrow * AST + c16 + 8] = z8;
      if (tid < 64) zpb[tid] = 0.f;
    }
  }
  __syncthreads();
  int w = tid >> 6, l = tid & 63;
  int fr = l & 15, fk = (l >> 4) * 8;
  int cr = (l >> 4) * 4, cn = l & 15;
  int ms = w * 16;
  bf16x8 qf0 = *(const bf16x8*)&Qa[(ms + fr) * AST + fk];
  bf16x8 qf1 = *(const bf16x8*)&Qa[(ms + fr) * AST + 32 + fk];
  f32x4 aqk[4] = {};
#pragma unroll
  for (int t = 0; t < 4; t++) {
    bf16x8 kf0 = *(const bf16x8*)&KA[(t * 16 + fr) * AST + fk];
    bf16x8 kf1 = *(const bf16x8*)&KA[(t * 16 + fr) * AST + 32 + fk];
    aqk[t] = __builtin_amdgcn_mfma_f32_16x16x32_bf16(qf0, kf0, aqk[t], 0, 0, 0);
    aqk[t] = __builtin_amdgcn_mfma_f32_16x16x32_bf16(qf1, kf1, aqk[t], 0, 0, 0);
  }
  __syncthreads();
  float rs[4] = {0.f, 0.f, 0.f, 0.f};
#pragma unroll
  for (int t = 0; t < 4; t++) {
#pragma unroll
    for (int r = 0; r < 4; r++) {
      int i = ms + cr + r;
      int j = t * 16 + cn;
      int dd = i > j ? i - j : j - i;
      float v = aqk[t][r] * pw[dd];
      rs[r] += v;
      KA[i * AST + j] = (bf16_t)v;
    }
  }
#pragma unroll
  for (int r = 0; r < 4; r++) rowpart[ms + cr + r][cn] = rs[r];
  __syncthreads();
  bf16x8 af0 = *(const bf16x8*)&KA[(ms + fr) * AST + fk];
  bf16x8 af1 = *(const bf16x8*)&KA[(ms + fr) * AST + 32 + fk];
  f32x4 aY[4] = {}, aSf[4] = {}, aSb[4] = {};
#pragma unroll
  for (int t = 0; t < 4; t++) {
    bf16x8 vf0 = *(const bf16x8*)&Vt[(t * 16 + fr) * AST + fk];
    bf16x8 vf1 = *(const bf16x8*)&Vt[(t * 16 + fr) * AST + 32 + fk];
    aY[t] = __builtin_amdgcn_mfma_f32_16x16x32_bf16(af0, vf0, aY[t], 0, 0, 0);
    aY[t] = __builtin_amdgcn_mfma_f32_16x16x32_bf16(af1, vf1, aY[t], 0, 0, 0);
    bf16x8 sf0 = *(const bf16x8*)&Sft[(t * 16 + fr) * AST + fk];
    bf16x8 sf1 = *(const bf16x8*)&Sft[(t * 16 + fr) * AST + 32 + fk];
    aSf[t] = __builtin_amdgcn_mfma_f32_16x16x32_bf16(qf0, sf0, aSf[t], 0, 0, 0);
    aSf[t] = __builtin_amdgcn_mfma_f32_16x16x32_bf16(qf1, sf1, aSf[t], 0, 0, 0);
    bf16x8 sb0 = *(const bf16x8*)&Sbt[(t * 16 + fr) * AST + fk];
    bf16x8 sb1 = *(const bf16x8*)&Sbt[(t * 16 + fr) * AST + 32 + fk];
    aSb[t] = __builtin_amdgcn_mfma_f32_16x16x32_bf16(qf0, sb0, aSb[t], 0, 0, 0);
    aSb[t] = __builtin_amdgcn_mfma_f32_16x16x32_bf16(qf1, sb1, aSb[t], 0, 0, 0);
  }
  // denominator, all 256 threads: 4 threads per row, shuffle-combine
  {
    int i = tid >> 2, p = tid & 3;
    float s = 0.f;
#pragma unroll
    for (int xx = 0; xx < 4; xx++) s += rowpart[i][p * 4 + xx];
    float czf = 0.f, czb = 0.f;
#pragma unroll
    for (int cc = 0; cc < 2; cc++) {
      int c = p * 16 + cc * 8;
      bf16x8 q8 = *(const bf16x8*)&Qa[i * AST + c];
#pragma unroll
      for (int u = 0; u < 8; u++) { czf += (float)q8[u] * zpf[c + u]; czb += (float)q8[u] * zpb[c + u]; }
    }
    float dsum = s + pw[i + 1] * czf + pw[64 - i] * czb;
    dsum += __shfl_xor(dsum, 1);
    dsum += __shfl_xor(dsum, 2);
    if (p == 0) den[i] = dsum;
  }
  __syncthreads();
#pragma unroll
  for (int t = 0; t < 4; t++) {
#pragma unroll
    for (int r = 0; r < 4; r++) {
      int i = ms + cr + r;
      int e = t * 16 + cn;
      float lrf = pw[i + 1], lrb = pw[64 - i];
      float inv = 1.f / fmaxf(den[i], 1e-6f);
      float val = (aY[t][r] + lrf * aSf[t][r] + lrb * aSb[t][r]) * inv;
      attnb[((size_t)(b * TT + t0 + i)) * DD + (size_t)h * 64 + e] = (bf16_t)val;
    }
  }
}

// ---------------------------------------------------------------- launch
extern "C" void kernel_launch(void* const* d_in, const int* in_sizes, int n_in,
                              void* d_out, int out_size, void* d_ws, size_t ws_size,
                              hipStream_t stream) {
  const float* x   = (const float*)d_in[0];
  const unsigned char* mask = (const unsigned char*)d_in[1];
  const float* Wq  = (const float*)d_in[2];
  const float* Wk  = (const float*)d_in[3];
  const float* Wv  = (const float*)d_in[4];
  const float* Wo  = (const float*)d_in[5];
  const float* bo  = (const float*)d_in[6];
  const float* g1  = (const float*)d_in[7];
  const float* b1  = (const float*)d_in[8];
  const float* g2  = (const float*)d_in[9];
  const float* b2  = (const float*)d_in[10];
  const float* W1  = (const float*)d_in[11];
  const float* bf1 = (const float*)d_in[12];
  const float* W2  = (const float*)d_in[13];
  const float* bf2 = (const float*)d_in[14];
  const float* dl  = (const float*)d_in[15];
  float* out = (float*)d_out;

  float* ws = (float*)d_ws;
  const size_t U = (size_t)BT * DD;  // 2097152 floats
  float* Qr  = ws;
  float* Kr  = ws + U;
  float* Vr  = ws + 2 * U;
  float* R3  = ws + 3 * U;
  float* R4  = ws + 4 * U;
  float* x2  = ws + 5 * U;
  bf16_t* Sstb = (bf16_t*)(ws + 6 * U);
  float* zst = ws + 8 * U;
  bf16_t* wall = (bf16_t*)(ws + 8 * U + 131072);
  bf16_t* Qb    = (bf16_t*)Qr;
  bf16_t* Kb    = (bf16_t*)Kr;
  bf16_t* Vb    = (bf16_t*)Vr;
  bf16_t* xnb   = (bf16_t*)R3;
  bf16_t* attnb = (bf16_t*)R4;
  bf16_t* h2b   = (bf16_t*)Qr;     // Qb dead after chunk_attn
  bf16_t* ffn1b = (bf16_t*)Kr;     // Kb+Vb dead after chunk_attn
  bf16_t* Wob = wall + 786432;
  bf16_t* W1b = wall + 1048576;
  bf16_t* W2b = wall + 2097152;

  ln_cast_kernel<<<1024 + 1536, 256, 0, stream>>>(x, g1, b1, xnb, Wq, Wk, Wv, Wo, W1, W2, wall);
  // QKV: M=4096, N=1536, K=512; 128x64 tiles -> 768 blocks = 3/CU
  gemm64q<<<768, 256, 0, stream>>>(xnb, wall, 512, 24, Qb, Kb, Vb, mask);
  chunk_summary_kernel<<<dim3(NC, 16), 256, 0, stream>>>(Kb, Vb, dl, Sstb, zst);
  scan_kernel<<<dim3(16, 16, 2), 256, 0, stream>>>(Sstb, zst, dl);
  chunk_attn_kernel<<<dim3(NC, 16), 256, 0, stream>>>(Qb, Kb, Vb, Sstb, zst, dl, attnb);
  // Wo: M=4096, N=512, K=512; 64x64 tiles -> 512 blocks = 2/CU; fused bias+resid -> fp32 x2
  gemm_s64<<<512, 256, 0, stream>>>(attnb, Wob, 512, 8, bo, x, x2);
  ln2_kernel<<<1024, 256, 0, stream>>>(x2, g2, b2, h2b);
  // FFN1: M=4096, N=2048, K=512; 128x128 tiles -> 512 blocks = 2/CU; GELU epilogue
  mfma_gemm<2><<<512, 256, 0, stream>>>(h2b, W1b, 512, 16, ffn1b, bf1);
  // FFN2: M=4096, N=512, K=2048; 64x64 tiles -> 512 blocks = 2/CU; fused bias+resid -> fp32 out
  gemm_s64<<<512, 256, 0, stream>>>(ffn1b, W2b, 2048, 8, bf2, x2, out);
}